// Round 9
// baseline (130.957 us; speedup 1.0000x reference)
//
#include <hip/hip_runtime.h>
#include <math.h>

// Problem constants
constexpr int Bn = 32;
constexpr int Cn = 512;
constexpr int Tn = 1024;
constexpr int KS = 13;

// Tiling
constexpr int CB   = 64;            // channels per block
constexpr int TT   = 64;            // timesteps per chunk
constexpr int NCH  = Tn / TT;       // 16 chunks
constexpr int DSTR = TT + 1;        // D row stride (odd -> conflict-free)
constexpr int NB   = 2;             // D ring depth
constexpr int NCW  = 4;             // conv waves
constexpr int SEG  = 16;            // output rows per conv thread
constexpr int HR   = SEG + KS - 1;  // 28 halo rows per conv thread

// 256 blocks (32 b x 8 c-groups) x 384 threads (6 waves), 1 block/CU.
// r8 post-mortem: register-resident prefetch dies at regalloc (loads sunk,
// distance->0). Here the input pipeline is global_load_lds DMA (zero VGPR
// cost, compiler cannot sink it): each conv wave issues 7 width-16 DMAs per
// chunk (its private 28-row halo) into a 3-slot LDS ring of DISTINCT named
// arrays X0/X1/X2 (unroll-by-3 -> compile-time slot binding, so the waitcnt
// pass can disambiguate slots and keep 2 chunks of DMAs in flight across the
// ds_reads). Handshakes: relaxed LDS atomics + explicit lgkmcnt(0) asm — no
// workgroup-release, hence NO vmcnt drain anywhere in the conv path.
// Roles: wave 0 scan (LDS only) | waves 1-4 conv (DMA + LDS) | wave 5 store
// (LDS + fire-and-forget global stores).
// All fp32 math uses explicit _rn intrinsics (one rounding per numpy op, no
// FMA) — bit-identical to the validated round-2..7 kernels. OOB halo rows:
// DMA address clamped, value replaced by 0 in registers via oob mask.

#define SCAN16(DV, TB)                                                   \
  _Pragma("unroll")                                                      \
  for (int j = 0; j < 16; ++j) {                                         \
    const float rthr = (mem > 0.5f) ? 0.5f : 0.0f;  /* reset: OLD mem */ \
    float a_  = __fmul_rn(0.95f, mem);                                   \
    float s2_ = __fadd_rn(a_, DV[j]);                                    \
    mem = __fsub_rn(s2_, rthr);                                          \
    const unsigned int bit = (mem > 0.5f) ? 1u : 0u;                     \
    if ((TB) + j < 32) lo |= bit << ((TB) + j);                          \
    else               hi |= bit << ((TB) + j - 32);                     \
  }

__global__ __launch_bounds__(384, 1)
void snn_fused(const float* __restrict__ x, const float* __restrict__ wp,
               float* __restrict__ out) {
  // X ring: three DISTINCT objects (alias-analysis disambiguation). 28 KB each.
  __shared__ float X0[NCW][HR][TT];
  __shared__ float X1[NCW][HR][TT];
  __shared__ float X2[NCW][HR][TT];
  __shared__ float D[NB][CB][DSTR];          // drive ring (33.3 KB)
  __shared__ unsigned long long Sb[NCH][CB]; // spike bitmasks (8 KB)
  __shared__ unsigned int prod[NB];
  __shared__ unsigned int scanProg;

  const int tid = threadIdx.x;
  const int b   = blockIdx.y;
  const int c0  = blockIdx.x * CB;
  const long xbase = (long)b * Cn * Tn;

  if (tid < NB) prod[tid] = 0u;
  if (tid == NB) scanProg = 0u;

  // ---- Gaussian weights, numpy float32 bit-emulation (validated) ----
  float kw[KS];
  {
    float w  = wp[0];
    float wc = fminf(fmaxf(w, 1.0f), 10.0f);      // clip(w, 1, 10)
    float sigma = __fadd_rn(5.5f, wc);
    float e[KS];
#pragma unroll
    for (int i = 0; i < KS; ++i) {
      float q = __fdiv_rn((float)(i - 6), sigma);
      float t = __fmul_rn(-0.5f, __fmul_rn(q, q));
      e[i] = (float)exp((double)t);
    }
    // numpy pairwise_sum order for n=13
    float s = __fadd_rn(
        __fadd_rn(__fadd_rn(e[0], e[1]), __fadd_rn(e[2], e[3])),
        __fadd_rn(__fadd_rn(e[4], e[5]), __fadd_rn(e[6], e[7])));
    s = __fadd_rn(s, e[8]);  s = __fadd_rn(s, e[9]);  s = __fadd_rn(s, e[10]);
    s = __fadd_rn(s, e[11]); s = __fadd_rn(s, e[12]);
#pragma unroll
    for (int i = 0; i < KS; ++i) kw[i] = __fdiv_rn(e[i], s);
  }

  __syncthreads();   // once: flags zeroed (before any DMA is issued)

  if (tid < 64) {
    // ======================= scan wave (consumer, LDS-only) =============
    const int c = tid;
    float mem = 0.0f;
    for (int k = 0; k < NCH; ++k) {
      const int slot = k & (NB - 1);
      const unsigned need = (unsigned)NCW * ((unsigned)(k >> 1) + 1u);
      while (__hip_atomic_load(&prod[slot], __ATOMIC_RELAXED,
                               __HIP_MEMORY_SCOPE_WORKGROUP) < need) {}
      __asm__ __volatile__("" ::: "memory");   // no hoisting above spin
      const float* Dc = &D[slot][c][0];
      unsigned int lo = 0u, hi = 0u;
      float dvA[16], dvB[16];                  // named arrays, const idx only
#pragma unroll
      for (int j = 0; j < 16; ++j) dvA[j] = Dc[j];
#pragma unroll
      for (int j = 0; j < 16; ++j) dvB[j] = Dc[16 + j];   // lookahead g=1
      SCAN16(dvA, 0)
#pragma unroll
      for (int j = 0; j < 16; ++j) dvA[j] = Dc[32 + j];   // lookahead g=2
      SCAN16(dvB, 16)
#pragma unroll
      for (int j = 0; j < 16; ++j) dvB[j] = Dc[48 + j];   // lookahead g=3
      SCAN16(dvA, 32)
      SCAN16(dvB, 48)
      Sb[k][c] = ((unsigned long long)hi << 32) | (unsigned long long)lo;
      __asm__ __volatile__("s_waitcnt lgkmcnt(0)" ::: "memory");
      if (tid == 0)
        __hip_atomic_fetch_add(&scanProg, 1u, __ATOMIC_RELAXED,
                               __HIP_MEMORY_SCOPE_WORKGROUP);
    }
  } else if (tid < 64 + 64 * NCW) {
    // ====== conv waves (producers): DMA global->LDS, conv, LDS writes =====
    const int ctid = tid - 64;
    const int col  = ctid & 63;               // t-column (lane)
    const int w    = ctid >> 6;               // conv wave 0..3
    const int segS = w * SEG;
    const int cin0 = c0 + segS - 6;

    // OOB mask for the 28 halo rows (wave-uniform)
    unsigned oobm = 0u;
#pragma unroll
    for (int j = 0; j < HR; ++j) {
      const int gc = cin0 + j;
      if (gc < 0 || gc >= Cn) oobm |= 1u << j;
    }
    // Per-lane DMA base pointers (t=0). Group g covers rows g*4..g*4+3:
    // lane reads 16B at row (g*4 + lane/16), cols (lane%16)*4..+3.
    const float* gp[7];
#pragma unroll
    for (int g = 0; g < 7; ++g) {
      int gc = cin0 + g * 4 + (col >> 4);
      gc = gc < 0 ? 0 : (gc > Cn - 1 ? Cn - 1 : gc);   // clamp (garbage ok)
      gp[g] = x + ((long)b * Cn + gc) * Tn + (col & 15) * 4;
    }

    auto dma = [&](int m, float (&Xs)[HR][TT]) {
#pragma unroll
      for (int g = 0; g < 7; ++g) {
        __builtin_amdgcn_global_load_lds(
            (const __attribute__((address_space(1))) void*)(gp[g] + m * TT),
            (__attribute__((address_space(3))) void*)(&Xs[g * 4][0]),
            16, 0, 0);
      }
    };
    auto convc = [&](float (&Xs)[HR][TT], int p) {
      float xs[HR];
#pragma unroll
      for (int j = 0; j < HR; ++j) {
        const float v = Xs[j][col];
        xs[j] = ((oobm >> j) & 1u) ? 0.0f : v;         // zero pad in regs
      }
#pragma unroll
      for (int r = 0; r < SEG; ++r) {
        float acc = __fmul_rn(kw[0], xs[r]);           // ascending, no FMA
#pragma unroll
        for (int i = 1; i < KS; ++i)
          acc = __fadd_rn(acc, __fmul_rn(kw[i], xs[r + i]));
        D[p][segS + r][col] = __fsub_rn(xs[r + 6], acc);   // x - x_mean
      }
    };
    auto waitD = [&](int K) {                  // D slot free?
      if (K >= NB) {
        const unsigned need = (unsigned)(K - NB + 1);
        while (__hip_atomic_load(&scanProg, __ATOMIC_RELAXED,
                                 __HIP_MEMORY_SCOPE_WORKGROUP) < need) {}
        __asm__ __volatile__("" ::: "memory");
      }
    };
    auto signal = [&](int K) {                 // LDS-ordered, NO vmcnt drain
      __asm__ __volatile__("s_waitcnt lgkmcnt(0)" ::: "memory");
      if (col == 0)
        __hip_atomic_fetch_add(&prod[K & (NB - 1)], 1u, __ATOMIC_RELAXED,
                               __HIP_MEMORY_SCOPE_WORKGROUP);
    };

    dma(0, X0[w]);
    dma(1, X1[w]);
#define STEP(K, XC, XN)                                                  \
    do {                                                                 \
      if ((K) + 2 < NCH) dma((K) + 2, XN[w]);                            \
      waitD(K);                                                          \
      convc(XC[w], (K) & (NB - 1));                                      \
      signal(K);                                                         \
    } while (0)
    for (int kb = 0; kb < NCH - 1; kb += 3) {  // kb=0,3,6,9,12 -> k=0..14
      STEP(kb + 0, X0, X2);
      STEP(kb + 1, X1, X0);
      STEP(kb + 2, X2, X1);
    }
    STEP(NCH - 1, X0, X2);                     // k=15 (15%3==0 -> X0)
#undef STEP
  } else {
    // ====== store wave (LDS reads + global stores, NEVER waits vmcnt) ===
    const int col = tid & 63;
    for (int k = 0; k < NCH; ++k) {
      while (__hip_atomic_load(&scanProg, __ATOMIC_RELAXED,
                               __HIP_MEMORY_SCOPE_WORKGROUP)
             < (unsigned)(k + 1)) {}
      __asm__ __volatile__("" ::: "memory");
      const int t0p = k * TT;
#pragma unroll 8
      for (int r = 0; r < CB; ++r) {
        const unsigned long long wb = Sb[k][r];          // LDS broadcast
        const float v = ((wb >> col) & 1ull) ? 1.0f : 0.0f;
        out[xbase + (long)(c0 + r) * Tn + t0p + col] = v; // fire & forget
      }
    }
  }
}

extern "C" void kernel_launch(void* const* d_in, const int* in_sizes, int n_in,
                              void* d_out, int out_size, void* d_ws, size_t ws_size,
                              hipStream_t stream) {
  const float* x  = (const float*)d_in[0];
  const float* w  = (const float*)d_in[1];
  float* out      = (float*)d_out;
  dim3 grid(Cn / CB, Bn, 1);
  snn_fused<<<grid, 384, 0, stream>>>(x, w, out);
}

// Round 10
// 128.754 us; speedup vs baseline: 1.0171x; 1.0171x over previous
//
#include <hip/hip_runtime.h>
#include <math.h>

// Problem constants
constexpr int Bn = 32;
constexpr int Cn = 512;
constexpr int Tn = 1024;
constexpr int KS = 13;

// Tiling
constexpr int CB   = 64;            // channels per block
constexpr int TT   = 64;            // timesteps per chunk
constexpr int NCH  = Tn / TT;       // 16 chunks
constexpr int DSTR = TT + 1;        // D row stride (odd -> conflict-free)
constexpr int NB   = 2;             // D ring depth
constexpr int NCW  = 4;             // conv waves
constexpr int SEG  = 16;            // output rows per conv thread
constexpr int HR   = SEG + KS - 1;  // 28 halo rows per conv thread
constexpr int XS   = 3;             // X ring slots
constexpr int XR   = CB + KS - 1;   // 76 rows per X slot (c0-6 .. c0+69)
constexpr int ND   = XR / 4;        // 19 width-16 DMAs per chunk

// 256 blocks (32 b x 8 c-groups) x 448 threads (7 waves), 1 block/CU.
// r7/r9 post-mortem: every prior structure had the VMEM-issuing wave also
// WAIT on vmcnt before per-chunk consumption -> queue drains to 0 each chunk
// -> latency-bound at 2.2 TB/s. Fix: vmcnt is per-wave, so DECOUPLE:
//   wave 6 (DMA)   : the ONLY wave with loop VMEM. Issues 19 global_load_lds
//                    per chunk into X[(k)%3], 2 chunks ahead (38-57 in
//                    flight, never drains), waits s_waitcnt vmcnt(38)
//                    (oldest chunk landed, 38 newer still in flight),
//                    signals xprog=k+1.
//   waves 1-4(conv): ZERO VMEM instructions -> compiler cannot insert any
//                    vmcnt wait. Pure LDS: read X slot, conv, write D ring.
//   wave 0 (scan)  : LDS only. Consumes D, packs spike bitmasks to Sb[k].
//   wave 5 (store) : LDS + fire-and-forget global stores (never waited).
// Handshakes: relaxed LDS atomics; per-chunk NO-REUSE counters dReady[k]
// (conv->scan, ==4) and consumed[k] (conv->DMA slot recycle, ==4); monotone
// xprog (DMA->conv) and scanProg (scan->conv/store). lgkmcnt(0) before each
// signal. All fp32 math uses explicit _rn intrinsics (one rounding per numpy
// op, no FMA) — bit-identical to the validated round-2..9 kernels.

#define SCAN16(DV, TB)                                                   \
  _Pragma("unroll")                                                      \
  for (int j = 0; j < 16; ++j) {                                         \
    const float rthr = (mem > 0.5f) ? 0.5f : 0.0f;  /* reset: OLD mem */ \
    float a_  = __fmul_rn(0.95f, mem);                                   \
    float s2_ = __fadd_rn(a_, DV[j]);                                    \
    mem = __fsub_rn(s2_, rthr);                                          \
    const unsigned int bit = (mem > 0.5f) ? 1u : 0u;                     \
    if ((TB) + j < 32) lo |= bit << ((TB) + j);                          \
    else               hi |= bit << ((TB) + j - 32);                     \
  }

#define SPIN_GE(ADDR, VAL)                                               \
  do {                                                                   \
    while (__hip_atomic_load((ADDR), __ATOMIC_RELAXED,                   \
                             __HIP_MEMORY_SCOPE_WORKGROUP) < (VAL)) {}   \
    __asm__ __volatile__("" ::: "memory");                               \
  } while (0)

__global__ __launch_bounds__(448, 1)
void snn_fused(const float* __restrict__ x, const float* __restrict__ wp,
               float* __restrict__ out) {
  __shared__ float X[XS][XR][TT];            // shared input ring (58.4 KB)
  __shared__ float D[NB][CB][DSTR];          // drive ring (33.3 KB)
  __shared__ unsigned long long Sb[NCH][CB]; // spike bitmasks (8 KB)
  __shared__ unsigned int dReady[NCH];       // conv->scan, no reuse
  __shared__ unsigned int consumed[NCH];     // conv->DMA,  no reuse
  __shared__ unsigned int xprog;             // DMA->conv (chunks ready)
  __shared__ unsigned int scanProg;          // scan->conv/store

  const int tid = threadIdx.x;
  const int b   = blockIdx.y;
  const int c0  = blockIdx.x * CB;
  const long xbase = (long)b * Cn * Tn;

  if (tid < NCH) { dReady[tid] = 0u; consumed[tid] = 0u; }
  if (tid == NCH)     xprog = 0u;
  if (tid == NCH + 1) scanProg = 0u;

  // ---- Gaussian weights, numpy float32 bit-emulation (validated) ----
  float kw[KS];
  {
    float w  = wp[0];
    float wc = fminf(fmaxf(w, 1.0f), 10.0f);      // clip(w, 1, 10)
    float sigma = __fadd_rn(5.5f, wc);
    float e[KS];
#pragma unroll
    for (int i = 0; i < KS; ++i) {
      float q = __fdiv_rn((float)(i - 6), sigma);
      float t = __fmul_rn(-0.5f, __fmul_rn(q, q));
      e[i] = (float)exp((double)t);
    }
    // numpy pairwise_sum order for n=13
    float s = __fadd_rn(
        __fadd_rn(__fadd_rn(e[0], e[1]), __fadd_rn(e[2], e[3])),
        __fadd_rn(__fadd_rn(e[4], e[5]), __fadd_rn(e[6], e[7])));
    s = __fadd_rn(s, e[8]);  s = __fadd_rn(s, e[9]);  s = __fadd_rn(s, e[10]);
    s = __fadd_rn(s, e[11]); s = __fadd_rn(s, e[12]);
#pragma unroll
    for (int i = 0; i < KS; ++i) kw[i] = __fdiv_rn(e[i], s);
  }

  __syncthreads();   // once: flags zeroed before any DMA

  const int w    = tid >> 6;   // wave role
  const int lane = tid & 63;

  if (w == 0) {
    // ======================= scan wave (LDS only) =======================
    const int c = lane;
    float mem = 0.0f;
    for (int k = 0; k < NCH; ++k) {
      SPIN_GE(&dReady[k], (unsigned)NCW);
      const float* Dc = &D[k & (NB - 1)][c][0];
      unsigned int lo = 0u, hi = 0u;
      float dvA[16], dvB[16];               // named arrays, const idx only
#pragma unroll
      for (int j = 0; j < 16; ++j) dvA[j] = Dc[j];
#pragma unroll
      for (int j = 0; j < 16; ++j) dvB[j] = Dc[16 + j];   // lookahead
      SCAN16(dvA, 0)
#pragma unroll
      for (int j = 0; j < 16; ++j) dvA[j] = Dc[32 + j];
      SCAN16(dvB, 16)
#pragma unroll
      for (int j = 0; j < 16; ++j) dvB[j] = Dc[48 + j];
      SCAN16(dvA, 32)
      SCAN16(dvB, 48)
      Sb[k][c] = ((unsigned long long)hi << 32) | (unsigned long long)lo;
      __asm__ __volatile__("s_waitcnt lgkmcnt(0)" ::: "memory");
      if (lane == 0)
        __hip_atomic_fetch_add(&scanProg, 1u, __ATOMIC_RELAXED,
                               __HIP_MEMORY_SCOPE_WORKGROUP);
    }
  } else if (w <= NCW) {
    // ============ conv waves (pure LDS consumers, NO VMEM) ==============
    const int g    = w - 1;
    const int segS = g * SEG;
    const int col  = lane;

    unsigned oobm = 0u;                      // OOB mask over 28 halo rows
#pragma unroll
    for (int j = 0; j < HR; ++j) {
      const int gc = c0 + segS - 6 + j;
      if (gc < 0 || gc >= Cn) oobm |= 1u << j;
    }

    for (int k = 0; k < NCH; ++k) {
      SPIN_GE(&xprog, (unsigned)(k + 1));
      const float* Xs = &X[k % XS][segS][0]; // rows segS..segS+27
      float xs[HR];
#pragma unroll
      for (int j = 0; j < HR; ++j) {
        const float v = Xs[j * TT + col];
        xs[j] = ((oobm >> j) & 1u) ? 0.0f : v;        // zero pad in regs
      }
      if (k >= NB) SPIN_GE(&scanProg, (unsigned)(k - NB + 1));
      float (*Dp)[DSTR] = D[k & (NB - 1)];
#pragma unroll
      for (int r = 0; r < SEG; ++r) {
        float acc = __fmul_rn(kw[0], xs[r]);          // ascending, no FMA
#pragma unroll
        for (int i = 1; i < KS; ++i)
          acc = __fadd_rn(acc, __fmul_rn(kw[i], xs[r + i]));
        Dp[segS + r][col] = __fsub_rn(xs[r + 6], acc);   // x - x_mean
      }
      __asm__ __volatile__("s_waitcnt lgkmcnt(0)" ::: "memory");
      if (col == 0) {
        __hip_atomic_fetch_add(&dReady[k], 1u, __ATOMIC_RELAXED,
                               __HIP_MEMORY_SCOPE_WORKGROUP);
        __hip_atomic_fetch_add(&consumed[k], 1u, __ATOMIC_RELAXED,
                               __HIP_MEMORY_SCOPE_WORKGROUP);
      }
    }
  } else if (w == NCW + 1) {
    // ====== store wave (LDS + global stores, never waits vmcnt) =========
    const int col = lane;
    for (int k = 0; k < NCH; ++k) {
      SPIN_GE(&scanProg, (unsigned)(k + 1));
      const int t0p = k * TT;
#pragma unroll 8
      for (int r = 0; r < CB; ++r) {
        const unsigned long long wb = Sb[k][r];          // LDS broadcast
        const float v = ((wb >> col) & 1ull) ? 1.0f : 0.0f;
        out[xbase + (long)(c0 + r) * Tn + t0p + col] = v; // fire & forget
      }
    }
  } else {
    // ====== DMA wave: the ONLY loop-VMEM wave; issue >> wait ============
    // Per-lane source pointers for the 19 row-groups (t=0), clamped at
    // tensor edge (garbage rows masked in conv waves).
    const float* gpd[ND];                    // const-indexed -> registers
#pragma unroll
    for (int d = 0; d < ND; ++d) {
      int gc = c0 - 6 + d * 4 + (lane >> 4);
      gc = gc < 0 ? 0 : (gc > Cn - 1 ? Cn - 1 : gc);
      gpd[d] = x + ((long)b * Cn + gc) * Tn + (lane & 15) * 4;
    }
    auto issue = [&](int m) {                // 19 DMAs for chunk m
      const int slot = m % XS;
#pragma unroll
      for (int d = 0; d < ND; ++d) {
        __builtin_amdgcn_global_load_lds(
            (const __attribute__((address_space(1))) void*)(gpd[d] + m * TT),
            (__attribute__((address_space(3))) void*)(&X[slot][d * 4][0]),
            16, 0, 0);
      }
    };

    issue(0);                                // 19 outstanding
    issue(1);                                // 38 outstanding
    for (int k = 0; k < NCH; ++k) {
      if (k + 2 < NCH) {
        if (k >= 1) SPIN_GE(&consumed[k - 1], (unsigned)NCW); // slot free
        issue(k + 2);                        // up to 57 outstanding
        __asm__ __volatile__("s_waitcnt vmcnt(38)" ::: "memory"); // k done
      } else if (k == NCH - 2) {
        __asm__ __volatile__("s_waitcnt vmcnt(19)" ::: "memory");
      } else {
        __asm__ __volatile__("s_waitcnt vmcnt(0)" ::: "memory");
      }
      if (lane == 0)
        __hip_atomic_fetch_add(&xprog, 1u, __ATOMIC_RELAXED,
                               __HIP_MEMORY_SCOPE_WORKGROUP);
    }
  }
}

extern "C" void kernel_launch(void* const* d_in, const int* in_sizes, int n_in,
                              void* d_out, int out_size, void* d_ws, size_t ws_size,
                              hipStream_t stream) {
  const float* x  = (const float*)d_in[0];
  const float* w  = (const float*)d_in[1];
  float* out      = (float*)d_out;
  dim3 grid(Cn / CB, Bn, 1);
  snn_fused<<<grid, 448, 0, stream>>>(x, w, out);
}